// Round 14
// baseline (96.217 us; speedup 1.0000x reference)
//
#include <hip/hip_runtime.h>
#include <hip/hip_bf16.h>

// Problem constants
#define BB 32
#define SS 256
#define DD 300
#define PDD 32
#define MM 66
#define FF 398      // D + PD + M
#define HH 6
#define G4 24       // 4*H
#define AA 12
#define L2E 1.4426950408889634f

__device__ __forceinline__ float fast_rcp(float x) { return __builtin_amdgcn_rcpf(x); }
__device__ __forceinline__ float bcast_lane(float x, int l) {
    return __int_as_float(__builtin_amdgcn_readlane(__float_as_int(x), l));
}
template<int CTRL>
__device__ __forceinline__ float quad_bcast(float v) {
    return __int_as_float(__builtin_amdgcn_mov_dpp(__float_as_int(v), CTRL, 0xf, 0xf, true));
}

// -------------------------------------------------------------------------
// Kernel 0: transpose Wx -> WT[dir][col][400] (k-contiguous, zero-padded).
// -------------------------------------------------------------------------
__global__ __launch_bounds__(256) void k_wtprep(
    const float* __restrict__ Wxf, const float* __restrict__ Wxb,
    float* __restrict__ WT)
{
    const float* Wx = blockIdx.x ? Wxb : Wxf;
    float* wt = WT + blockIdx.x * (G4 * 400);
    int t = threadIdx.x;
    for (int idx = t; idx < FF * G4; idx += 256) {
        int k = idx / G4, j = idx % G4;
        wt[j * 400 + k] = Wx[idx];
    }
    if (t < 2 * G4) {                    // zero pad k = 398, 399
        int j = t >> 1, k = 398 + (t & 1);
        wt[j * 400 + k] = 0.f;
    }
}

// -------------------------------------------------------------------------
// Kernel 1 (v6): embed+concat+projection. Feats staged transposed in LDS
// (only LDS user -> ds pipe ~400 b128/CU); W streams from global WT via
// VMEM vector loads (separate vmcnt pipe; per-wave 2 distinct addrs,
// HW-coalesced, L2-hot 9.6KB/wave streamed once). NOTE: col-group index is
// NOT readfirstlane'd -- keeping it formally divergent prevents the
// compiler scalarizing W loads to s_load (R12 regression: SMEM shares
// lgkmcnt with ds_read -> serializing waits).
// Epilogue folds bias + the lstm's +-log2e gate prescale.
// -------------------------------------------------------------------------
#define EPB 32
__global__ __launch_bounds__(256) void k_embed_proj(
    const int* __restrict__ words, const int* __restrict__ pos,
    const float* __restrict__ morph, const float* __restrict__ wtab,
    const float* __restrict__ ptab, const float* __restrict__ WT,
    const float* __restrict__ bfv, const float* __restrict__ bbv,
    float* __restrict__ xgf, float* __restrict__ xgb)
{
    __shared__ float4 sF[100][33];      // 52.8 KB
    int t  = threadIdx.x;
    int p0 = blockIdx.x * EPB;

    for (int idx = t; idx < EPB * 75; idx += 256) {
        int p = idx / 75, q = idx % 75;
        sF[q][p] = *(const float4*)(wtab + (size_t)words[p0 + p] * DD + 4 * q);
    }
    {
        int idx = t;                    // EPB*8 = 256 exactly
        int p = idx / 8, q = idx % 8;
        sF[75 + q][p] = *(const float4*)(ptab + pos[p0 + p] * PDD + 4 * q);
    }
    for (int idx = t; idx < EPB * 17; idx += 256) {
        int p = idx / 17, mq = idx % 17;
        const float2* ms = (const float2*)(morph + (size_t)(p0 + p) * MM);
        float2 lo = ms[2 * mq];
        float2 hi = (mq < 16) ? ms[2 * mq + 1] : make_float2(0.f, 0.f);
        sF[83 + mq][p] = make_float4(lo.x, lo.y, hi.x, hi.y);
    }
    __syncthreads();

    int lane = t & 63, w = t >> 6;
    int p    = lane & 31;
    int cg   = w * 2 + (lane >> 5);     // 0..7 (NOT readfirstlane'd!)
    int dir  = cg >> 2;
    int tg   = cg & 3;
    int j0   = tg * 6;
    const float4* wc = (const float4*)(WT + (size_t)(dir * G4 + j0) * 400);

    float a0 = 0.f, a1 = 0.f, a2 = 0.f, a3 = 0.f, a4 = 0.f, a5 = 0.f;
    #pragma unroll 4
    for (int q = 0; q < 100; ++q) {
        float4 f = sF[q][p];
        float4 w0 = wc[0 * 100 + q], w1 = wc[1 * 100 + q], w2 = wc[2 * 100 + q];
        float4 w3 = wc[3 * 100 + q], w4 = wc[4 * 100 + q], w5 = wc[5 * 100 + q];
        a0 = fmaf(f.x, w0.x, a0); a0 = fmaf(f.y, w0.y, a0);
        a0 = fmaf(f.z, w0.z, a0); a0 = fmaf(f.w, w0.w, a0);
        a1 = fmaf(f.x, w1.x, a1); a1 = fmaf(f.y, w1.y, a1);
        a1 = fmaf(f.z, w1.z, a1); a1 = fmaf(f.w, w1.w, a1);
        a2 = fmaf(f.x, w2.x, a2); a2 = fmaf(f.y, w2.y, a2);
        a2 = fmaf(f.z, w2.z, a2); a2 = fmaf(f.w, w2.w, a2);
        a3 = fmaf(f.x, w3.x, a3); a3 = fmaf(f.y, w3.y, a3);
        a3 = fmaf(f.z, w3.z, a3); a3 = fmaf(f.w, w3.w, a3);
        a4 = fmaf(f.x, w4.x, a4); a4 = fmaf(f.y, w4.y, a4);
        a4 = fmaf(f.z, w4.z, a4); a4 = fmaf(f.w, w4.w, a4);
        a5 = fmaf(f.x, w5.x, a5); a5 = fmaf(f.y, w5.y, a5);
        a5 = fmaf(f.z, w5.z, a5); a5 = fmaf(f.w, w5.w, a5);
    }

    float kk = (tg == 2) ? 2.f * L2E : -L2E;
    const float* bias = dir ? bbv : bfv;
    float* o = (dir ? xgb : xgf) + (size_t)(p0 + p) * G4 + j0;
    o[0] = (a0 + bias[j0 + 0]) * kk; o[1] = (a1 + bias[j0 + 1]) * kk;
    o[2] = (a2 + bias[j0 + 2]) * kk; o[3] = (a3 + bias[j0 + 3]) * kk;
    o[4] = (a4 + bias[j0 + 4]) * kk; o[5] = (a5 + bias[j0 + 5]) * kk;
}

// -------------------------------------------------------------------------
// Kernel 2 (v12+prescale): LSTM + uawa fused (R13 structure). Block = one
// batch, 2 waves = fwd/bwd chains on separate SIMDs. Epilogue computes
// ua/wa PRESCALED by 2*log2e for k_score's exp2-based tanh.
// -------------------------------------------------------------------------
__global__ __launch_bounds__(128) void k_lstm_uawa(
    const float* __restrict__ xgf, const float* __restrict__ xgb,
    const float* __restrict__ Whf, const float* __restrict__ Whb,
    const float* __restrict__ Wu, const float* __restrict__ bu,
    const float* __restrict__ Ww, const float* __restrict__ bw,
    float* __restrict__ ua, float* __restrict__ wa)
{
    __shared__ float sxg[2][(SS + 8) * G4];   // 50.7 KB
    __shared__ float hbuf[2][SS * HH];        // 12 KB
    int b    = blockIdx.x;                    // 0..31
    int lane = threadIdx.x & 63;
    int dir  = __builtin_amdgcn_readfirstlane(threadIdx.x >> 6);

    const float* xg = (dir ? xgb : xgf) + (size_t)b * SS * G4;
    const float* Wh = dir ? Whb : Whf;

    {
        const float4* src = (const float4*)xg;
        float4* dst = (float4*)sxg[dir];
        #pragma unroll
        for (int u = 0; u < 24; ++u) {
            int d = lane + u * 64;            // float4 index 0..1535
            int row = d / 6, c4 = d - row * 6;
            int drow = dir ? (SS - 1 - row) : row;
            dst[drow * 6 + c4] = src[d];
        }
        for (int g2 = lane; g2 < 8 * G4; g2 += 64) sxg[dir][SS * G4 + g2] = 0.f;
    }

    int g    = lane % G4;                   // gate slot 0..23
    int cell = g >> 2;                      // 0..5
    int type = g & 3;                       // 0=i 1=f 2=c 3=o
    int j    = type * HH + cell;            // keras column

    float kk = (type == 2) ? 2.f * L2E : -L2E;
    float wh[HH];
    #pragma unroll
    for (int m = 0; m < HH; ++m) wh[m] = Wh[m * G4 + j] * kk;
    float Bc = (type == 2) ? 1.f : 0.f;
    float Ac = (type == 2) ? -1.f : 1.f;

    float sh[HH];
    #pragma unroll
    for (int m = 0; m < HH; ++m) sh[m] = 0.f;
    float c = 0.f;
    bool wr = (lane < G4) && ((lane & 3) == 0);

    const float* xb = sxg[dir] + j;
    float* hb = hbuf[dir];

    float pg[4];
    #pragma unroll
    for (int sl = 0; sl < 4; ++sl) pg[sl] = xb[sl * G4];

    #pragma unroll 1
    for (int t = 0; t < SS; t += 4) {
        #pragma unroll
        for (int sl = 0; sl < 4; ++sl) {
            float x = pg[sl];
            pg[sl] = xb[(t + 4 + sl) * G4];      // guard rows cover the tail

            float aa  = fmaf(sh[1], wh[1], fmaf(sh[0], wh[0], x));
            float bb2 = fmaf(sh[3], wh[3], sh[2] * wh[2]);
            float cc2 = fmaf(sh[5], wh[5], sh[4] * wh[4]);
            x = (aa + bb2) + cc2;

            float e   = __builtin_amdgcn_exp2f(x);
            float val = fmaf(Bc, e, Ac) * fast_rcp(1.f + e);

            float vi = quad_bcast<0>(val);
            float vf = quad_bcast<85>(val);
            float vc = quad_bcast<170>(val);
            float vo = quad_bcast<255>(val);

            c = fmaf(vf, c, vi * vc);
            float ec = __builtin_amdgcn_exp2f(c * (2.f * L2E));
            float h  = (ec - 1.f) * fast_rcp(ec + 1.f) * vo;

            if (wr) hb[(t + sl) * HH + cell] = h;
            #pragma unroll
            for (int m = 0; m < HH; ++m) sh[m] = bcast_lane(h, 4 * m);
        }
    }
    __syncthreads();

    // epilogue: ua/wa (prescaled 2*log2e) for this batch's 256 positions.
    #pragma unroll
    for (int half = 0; half < 2; ++half) {
        int s = (int)threadIdx.x + half * 128;
        float r[AA];
        #pragma unroll
        for (int cc = 0; cc < HH; ++cc) {
            r[cc]      = hbuf[0][s * HH + cc];
            r[HH + cc] = hbuf[1][(SS - 1 - s) * HH + cc];
        }
        float au[AA], aw[AA];
        #pragma unroll
        for (int d = 0; d < AA; ++d) { au[d] = bu[d]; aw[d] = bw[d]; }
        #pragma unroll
        for (int e2 = 0; e2 < AA; ++e2) {
            #pragma unroll
            for (int d = 0; d < AA; ++d) {
                au[d] = fmaf(r[e2], Wu[e2 * AA + d], au[d]);
                aw[d] = fmaf(r[e2], Ww[e2 * AA + d], aw[d]);
            }
        }
        float* ou = ua + ((size_t)b * SS + s) * AA;
        float* ow = wa + ((size_t)b * SS + s) * AA;
        #pragma unroll
        for (int d4 = 0; d4 < 3; ++d4) {
            *(float4*)(ou + 4 * d4) = make_float4(au[4*d4] * (2.f*L2E), au[4*d4+1] * (2.f*L2E),
                                                  au[4*d4+2] * (2.f*L2E), au[4*d4+3] * (2.f*L2E));
            *(float4*)(ow + 4 * d4) = make_float4(aw[4*d4] * (2.f*L2E), aw[4*d4+1] * (2.f*L2E),
                                                  aw[4*d4+2] * (2.f*L2E), aw[4*d4+3] * (2.f*L2E));
        }
    }
}

// -------------------------------------------------------------------------
// Kernel 4 (v3): arc scores, 4 dependants i per block (grid 2048).
// ua row (prescaled 2log2e) loaded ONCE per thread, reused for 4 i's
// (ua traffic /4). tanh(u+w) = 1 - 2*rcp(1+exp2(ua'+wa')):
// s = sumv - 2*sum_d v_d * rcp(1+exp2(us_d+swa_d)). Single barrier.
// -------------------------------------------------------------------------
__global__ __launch_bounds__(256) void k_score(
    const float* __restrict__ ua, const float* __restrict__ wa,
    const float* __restrict__ v, const int* __restrict__ heads,
    float* __restrict__ out, float* __restrict__ ce)
{
    int blk = blockIdx.x;           // b*64 + ig
    int b   = blk >> 6;
    int i0  = (blk & 63) * 4;
    int j   = threadIdx.x;
    int w   = j >> 6;

    __shared__ float swa[4][AA], sv[AA];
    __shared__ float part[4][4];
    if (j < 4 * AA) swa[j / AA][j % AA] = wa[((size_t)b * SS + i0 + j / AA) * AA + j % AA];
    if (j < AA) sv[j] = v[j];
    __syncthreads();

    float sumv = 0.f;
    #pragma unroll
    for (int d = 0; d < AA; ++d) sumv += sv[d];

    const float* uj = ua + ((size_t)b * SS + j) * AA;
    float4 u0 = *(const float4*)(uj);
    float4 u1 = *(const float4*)(uj + 4);
    float4 u2 = *(const float4*)(uj + 8);
    float us[AA] = {u0.x, u0.y, u0.z, u0.w, u1.x, u1.y, u1.z, u1.w,
                    u2.x, u2.y, u2.z, u2.w};

    float sv_[4];
    #pragma unroll
    for (int ii = 0; ii < 4; ++ii) {
        int i = i0 + ii;
        float acc = 0.f;
        #pragma unroll
        for (int d = 0; d < AA; ++d) {
            float e_d = __builtin_amdgcn_exp2f(us[d] + swa[ii][d]);
            acc = fmaf(sv[d], fast_rcp(1.f + e_d), acc);
        }
        float s = fmaf(-2.f, acc, sumv);
        if (j == i) s = -10000.f;
        sv_[ii] = s;

        float e = __builtin_amdgcn_exp2f(s * L2E);
        if (i >= 1)
            out[1 + (((size_t)(i - 1) * BB + b) * SS + j)] = e;

        float r = e;
        #pragma unroll
        for (int off = 32; off > 0; off >>= 1) r += __shfl_xor(r, off, 64);
        if ((j & 63) == 0) part[ii][w] = r;
    }
    __syncthreads();

    #pragma unroll
    for (int ii = 0; ii < 4; ++ii) {
        int i = i0 + ii;
        float tot = part[ii][0] + part[ii][1] + part[ii][2] + part[ii][3];
        if (j == heads[b * SS + i])
            ce[b * SS + i] = (i >= 1) ? (__logf(tot) - sv_[ii]) : 0.f;
    }
}

// -------------------------------------------------------------------------
// Kernel 5: deterministic loss reduction: sum(ce)/B into out[0].
// -------------------------------------------------------------------------
__global__ __launch_bounds__(256) void k_loss(const float* __restrict__ ce,
                                              float* __restrict__ out)
{
    __shared__ float red[256];
    int t = threadIdx.x;
    float a = 0.f;
    for (int k = t; k < BB * SS; k += 256) a += ce[k];
    red[t] = a; __syncthreads();
    for (int off = 128; off > 0; off >>= 1) {
        if (t < off) red[t] += red[t + off];
        __syncthreads();
    }
    if (t == 0) out[0] = red[0] * (1.f / BB);
}

extern "C" void kernel_launch(void* const* d_in, const int* in_sizes, int n_in,
                              void* d_out, int out_size, void* d_ws, size_t ws_size,
                              hipStream_t stream)
{
    const int*   words = (const int*)  d_in[0];
    const int*   pos   = (const int*)  d_in[1];
    const float* morph = (const float*)d_in[2];
    const int*   heads = (const int*)  d_in[3];
    const float* wtab  = (const float*)d_in[4];
    const float* ptab  = (const float*)d_in[5];
    const float* Wxf   = (const float*)d_in[6];
    const float* Whf   = (const float*)d_in[7];
    const float* bf    = (const float*)d_in[8];
    const float* Wxb   = (const float*)d_in[9];
    const float* Whb   = (const float*)d_in[10];
    const float* bb    = (const float*)d_in[11];
    const float* Wu    = (const float*)d_in[12];
    const float* bu    = (const float*)d_in[13];
    const float* Ww    = (const float*)d_in[14];
    const float* bw    = (const float*)d_in[15];
    const float* v     = (const float*)d_in[16];
    float* out = (float*)d_out;

    // workspace layout (floats)
    float* xgf  = (float*)d_ws;                  // 8192*24 (prescaled)
    float* xgb  = xgf  + (size_t)BB*SS*G4;       // 8192*24 (prescaled)
    float* ua   = xgb  + (size_t)BB*SS*G4;       // 8192*12 (prescaled 2log2e)
    float* wa   = ua   + (size_t)BB*SS*AA;       // 8192*12 (prescaled 2log2e)
    float* ce   = wa   + (size_t)BB*SS*AA;       // 8192
    float* WT   = ce   + (size_t)BB*SS;          // 2*24*400

    k_wtprep<<<2, 256, 0, stream>>>(Wxf, Wxb, WT);
    k_embed_proj<<<(BB * SS) / EPB, 256, 0, stream>>>(words, pos, morph, wtab, ptab,
                                                      WT, bf, bb, xgf, xgb);
    k_lstm_uawa<<<BB, 128, 0, stream>>>(xgf, xgb, Whf, Whb, Wu, bu, Ww, bw, ua, wa);
    k_score<<<BB * (SS / 4), 256, 0, stream>>>(ua, wa, v, heads, out, ce);
    k_loss<<<1, 256, 0, stream>>>(ce, out);
}

// Round 15
// 72.569 us; speedup vs baseline: 1.3259x; 1.3259x over previous
//
#include <hip/hip_runtime.h>
#include <hip/hip_bf16.h>

// Problem constants
#define BB 32
#define SS 256
#define DD 300
#define PDD 32
#define MM 66
#define FF 398      // D + PD + M
#define HH 6
#define G4 24       // 4*H
#define AA 12
#define L2E 1.4426950408889634f

__device__ __forceinline__ float fast_rcp(float x) { return __builtin_amdgcn_rcpf(x); }
__device__ __forceinline__ float bcast_lane(float x, int l) {
    return __int_as_float(__builtin_amdgcn_readlane(__float_as_int(x), l));
}
template<int CTRL>
__device__ __forceinline__ float quad_bcast(float v) {
    return __int_as_float(__builtin_amdgcn_mov_dpp(__float_as_int(v), CTRL, 0xf, 0xf, true));
}

// -------------------------------------------------------------------------
// Kernel 1 (R9-verbatim): fused embed+concat+projection, all-LDS.
// Block = 32 positions, 256 thr, grid 256 (1 block/CU). Feats transposed in
// LDS; all of W in LDS. Epilogue folds bias + the lstm's +-log2e prescale.
// (R12/R14 lesson: W must come from LDS — s_load collides with ds_read on
// lgkmcnt; VMEM broadcast loads pay full per-wave issue+latency.)
// -------------------------------------------------------------------------
#define EPB 32
__global__ __launch_bounds__(256) void k_embed_proj(
    const int* __restrict__ words, const int* __restrict__ pos,
    const float* __restrict__ morph, const float* __restrict__ wtab,
    const float* __restrict__ ptab,
    const float* __restrict__ Wxf, const float* __restrict__ bfv,
    const float* __restrict__ Wxb, const float* __restrict__ bbv,
    float* __restrict__ xgf, float* __restrict__ xgb)
{
    __shared__ float4 sF[100][33];      // 52.8 KB
    __shared__ float4 sW[48 * 100];     // 76.8 KB
    int t  = threadIdx.x;
    int p0 = blockIdx.x * EPB;

    for (int idx = t; idx < EPB * 75; idx += 256) {
        int p = idx / 75, q = idx % 75;
        sF[q][p] = *(const float4*)(wtab + (size_t)words[p0 + p] * DD + 4 * q);
    }
    {
        int idx = t;                    // EPB*8 = 256 exactly
        int p = idx / 8, q = idx % 8;
        sF[75 + q][p] = *(const float4*)(ptab + pos[p0 + p] * PDD + 4 * q);
    }
    for (int idx = t; idx < EPB * 17; idx += 256) {
        int p = idx / 17, mq = idx % 17;
        const float2* ms = (const float2*)(morph + (size_t)(p0 + p) * MM);
        float2 lo = ms[2 * mq];
        float2 hi = (mq < 16) ? ms[2 * mq + 1] : make_float2(0.f, 0.f);
        sF[83 + mq][p] = make_float4(lo.x, lo.y, hi.x, hi.y);
    }
    {
        float* sWf = (float*)sW;
        for (int idx = t; idx < FF * G4; idx += 256) {
            int k = idx / G4, j = idx % G4;
            sWf[j * 400 + k]        = Wxf[idx];
            sWf[(24 + j) * 400 + k] = Wxb[idx];
        }
        if (t < 2 * G4) {
            int j = t >> 1, k = 398 + (t & 1);
            sWf[j * 400 + k] = 0.f; sWf[(24 + j) * 400 + k] = 0.f;
        }
    }
    __syncthreads();

    int lane = t & 63, w = t >> 6;
    int p    = lane & 31;
    int cg   = w * 2 + (lane >> 5);
    int dir  = cg >> 2;
    int tg   = cg & 3;
    int j0   = tg * 6;
    const float4* wc = sW + (dir * 24 + j0) * 100;

    float a0 = 0.f, a1 = 0.f, a2 = 0.f, a3 = 0.f, a4 = 0.f, a5 = 0.f;
    #pragma unroll 4
    for (int q = 0; q < 100; ++q) {
        float4 f = sF[q][p];
        float4 w0 = wc[0 * 100 + q], w1 = wc[1 * 100 + q], w2 = wc[2 * 100 + q];
        float4 w3 = wc[3 * 100 + q], w4 = wc[4 * 100 + q], w5 = wc[5 * 100 + q];
        a0 = fmaf(f.x, w0.x, a0); a0 = fmaf(f.y, w0.y, a0);
        a0 = fmaf(f.z, w0.z, a0); a0 = fmaf(f.w, w0.w, a0);
        a1 = fmaf(f.x, w1.x, a1); a1 = fmaf(f.y, w1.y, a1);
        a1 = fmaf(f.z, w1.z, a1); a1 = fmaf(f.w, w1.w, a1);
        a2 = fmaf(f.x, w2.x, a2); a2 = fmaf(f.y, w2.y, a2);
        a2 = fmaf(f.z, w2.z, a2); a2 = fmaf(f.w, w2.w, a2);
        a3 = fmaf(f.x, w3.x, a3); a3 = fmaf(f.y, w3.y, a3);
        a3 = fmaf(f.z, w3.z, a3); a3 = fmaf(f.w, w3.w, a3);
        a4 = fmaf(f.x, w4.x, a4); a4 = fmaf(f.y, w4.y, a4);
        a4 = fmaf(f.z, w4.z, a4); a4 = fmaf(f.w, w4.w, a4);
        a5 = fmaf(f.x, w5.x, a5); a5 = fmaf(f.y, w5.y, a5);
        a5 = fmaf(f.z, w5.z, a5); a5 = fmaf(f.w, w5.w, a5);
    }

    float kk = (tg == 2) ? 2.f * L2E : -L2E;
    const float* bias = dir ? bbv : bfv;
    float* o = (dir ? xgb : xgf) + (size_t)(p0 + p) * G4 + j0;
    o[0] = (a0 + bias[j0 + 0]) * kk; o[1] = (a1 + bias[j0 + 1]) * kk;
    o[2] = (a2 + bias[j0 + 2]) * kk; o[3] = (a3 + bias[j0 + 3]) * kk;
    o[4] = (a4 + bias[j0 + 4]) * kk; o[5] = (a5 + bias[j0 + 5]) * kk;
}

// -------------------------------------------------------------------------
// Kernel 2 (R13 + prescale epilogue): LSTM + uawa fused. Block = one batch,
// 2 waves = fwd/bwd chains on separate SIMDs (full parallel latency).
// Epilogue computes ua/wa PRESCALED by 2*log2e for k_score's exp2 tanh.
// -------------------------------------------------------------------------
__global__ __launch_bounds__(128) void k_lstm_uawa(
    const float* __restrict__ xgf, const float* __restrict__ xgb,
    const float* __restrict__ Whf, const float* __restrict__ Whb,
    const float* __restrict__ Wu, const float* __restrict__ bu,
    const float* __restrict__ Ww, const float* __restrict__ bw,
    float* __restrict__ ua, float* __restrict__ wa)
{
    __shared__ float sxg[2][(SS + 8) * G4];   // 50.7 KB
    __shared__ float hbuf[2][SS * HH];        // 12 KB
    int b    = blockIdx.x;                    // 0..31
    int lane = threadIdx.x & 63;
    int dir  = __builtin_amdgcn_readfirstlane(threadIdx.x >> 6);

    const float* xg = (dir ? xgb : xgf) + (size_t)b * SS * G4;
    const float* Wh = dir ? Whb : Whf;

    {
        const float4* src = (const float4*)xg;
        float4* dst = (float4*)sxg[dir];
        #pragma unroll
        for (int u = 0; u < 24; ++u) {
            int d = lane + u * 64;            // float4 index 0..1535
            int row = d / 6, c4 = d - row * 6;
            int drow = dir ? (SS - 1 - row) : row;
            dst[drow * 6 + c4] = src[d];
        }
        for (int g2 = lane; g2 < 8 * G4; g2 += 64) sxg[dir][SS * G4 + g2] = 0.f;
    }

    int g    = lane % G4;                   // gate slot 0..23
    int cell = g >> 2;                      // 0..5
    int type = g & 3;                       // 0=i 1=f 2=c 3=o
    int j    = type * HH + cell;            // keras column

    float kk = (type == 2) ? 2.f * L2E : -L2E;
    float wh[HH];
    #pragma unroll
    for (int m = 0; m < HH; ++m) wh[m] = Wh[m * G4 + j] * kk;
    float Bc = (type == 2) ? 1.f : 0.f;
    float Ac = (type == 2) ? -1.f : 1.f;

    float sh[HH];
    #pragma unroll
    for (int m = 0; m < HH; ++m) sh[m] = 0.f;
    float c = 0.f;
    bool wr = (lane < G4) && ((lane & 3) == 0);

    const float* xb = sxg[dir] + j;
    float* hb = hbuf[dir];

    float pg[4];
    #pragma unroll
    for (int sl = 0; sl < 4; ++sl) pg[sl] = xb[sl * G4];

    #pragma unroll 1
    for (int t = 0; t < SS; t += 4) {
        #pragma unroll
        for (int sl = 0; sl < 4; ++sl) {
            float x = pg[sl];
            pg[sl] = xb[(t + 4 + sl) * G4];      // guard rows cover the tail

            float aa  = fmaf(sh[1], wh[1], fmaf(sh[0], wh[0], x));
            float bb2 = fmaf(sh[3], wh[3], sh[2] * wh[2]);
            float cc2 = fmaf(sh[5], wh[5], sh[4] * wh[4]);
            x = (aa + bb2) + cc2;

            float e   = __builtin_amdgcn_exp2f(x);
            float val = fmaf(Bc, e, Ac) * fast_rcp(1.f + e);

            float vi = quad_bcast<0>(val);
            float vf = quad_bcast<85>(val);
            float vc = quad_bcast<170>(val);
            float vo = quad_bcast<255>(val);

            c = fmaf(vf, c, vi * vc);
            float ec = __builtin_amdgcn_exp2f(c * (2.f * L2E));
            float h  = (ec - 1.f) * fast_rcp(ec + 1.f) * vo;

            if (wr) hb[(t + sl) * HH + cell] = h;
            #pragma unroll
            for (int m = 0; m < HH; ++m) sh[m] = bcast_lane(h, 4 * m);
        }
    }
    __syncthreads();

    // epilogue: ua/wa (prescaled 2*log2e) for this batch's 256 positions.
    #pragma unroll
    for (int half = 0; half < 2; ++half) {
        int s = (int)threadIdx.x + half * 128;
        float r[AA];
        #pragma unroll
        for (int cc = 0; cc < HH; ++cc) {
            r[cc]      = hbuf[0][s * HH + cc];
            r[HH + cc] = hbuf[1][(SS - 1 - s) * HH + cc];
        }
        float au[AA], aw[AA];
        #pragma unroll
        for (int d = 0; d < AA; ++d) { au[d] = bu[d]; aw[d] = bw[d]; }
        #pragma unroll
        for (int e2 = 0; e2 < AA; ++e2) {
            #pragma unroll
            for (int d = 0; d < AA; ++d) {
                au[d] = fmaf(r[e2], Wu[e2 * AA + d], au[d]);
                aw[d] = fmaf(r[e2], Ww[e2 * AA + d], aw[d]);
            }
        }
        float* ou = ua + ((size_t)b * SS + s) * AA;
        float* ow = wa + ((size_t)b * SS + s) * AA;
        #pragma unroll
        for (int d4 = 0; d4 < 3; ++d4) {
            *(float4*)(ou + 4 * d4) = make_float4(au[4*d4] * (2.f*L2E), au[4*d4+1] * (2.f*L2E),
                                                  au[4*d4+2] * (2.f*L2E), au[4*d4+3] * (2.f*L2E));
            *(float4*)(ow + 4 * d4) = make_float4(aw[4*d4] * (2.f*L2E), aw[4*d4+1] * (2.f*L2E),
                                                  aw[4*d4+2] * (2.f*L2E), aw[4*d4+3] * (2.f*L2E));
        }
    }
}

// -------------------------------------------------------------------------
// Kernel 4 (v3, from R14 — correctness-verified): arc scores, 4 dependants
// per block (grid 2048). ua row loaded ONCE, reused for 4 i's. tanh via
// exp2 on prescaled inputs: s = sumv - 2*sum_d v_d*rcp(1+exp2(us_d+swa_d)).
// -------------------------------------------------------------------------
__global__ __launch_bounds__(256) void k_score(
    const float* __restrict__ ua, const float* __restrict__ wa,
    const float* __restrict__ v, const int* __restrict__ heads,
    float* __restrict__ out, float* __restrict__ ce)
{
    int blk = blockIdx.x;           // b*64 + ig
    int b   = blk >> 6;
    int i0  = (blk & 63) * 4;
    int j   = threadIdx.x;
    int w   = j >> 6;

    __shared__ float swa[4][AA], sv[AA];
    __shared__ float part[4][4];
    if (j < 4 * AA) swa[j / AA][j % AA] = wa[((size_t)b * SS + i0 + j / AA) * AA + j % AA];
    if (j < AA) sv[j] = v[j];
    __syncthreads();

    float sumv = 0.f;
    #pragma unroll
    for (int d = 0; d < AA; ++d) sumv += sv[d];

    const float* uj = ua + ((size_t)b * SS + j) * AA;
    float4 u0 = *(const float4*)(uj);
    float4 u1 = *(const float4*)(uj + 4);
    float4 u2 = *(const float4*)(uj + 8);
    float us[AA] = {u0.x, u0.y, u0.z, u0.w, u1.x, u1.y, u1.z, u1.w,
                    u2.x, u2.y, u2.z, u2.w};

    float sv_[4];
    #pragma unroll
    for (int ii = 0; ii < 4; ++ii) {
        int i = i0 + ii;
        float acc = 0.f;
        #pragma unroll
        for (int d = 0; d < AA; ++d) {
            float e_d = __builtin_amdgcn_exp2f(us[d] + swa[ii][d]);
            acc = fmaf(sv[d], fast_rcp(1.f + e_d), acc);
        }
        float s = fmaf(-2.f, acc, sumv);
        if (j == i) s = -10000.f;
        sv_[ii] = s;

        float e = __builtin_amdgcn_exp2f(s * L2E);
        if (i >= 1)
            out[1 + (((size_t)(i - 1) * BB + b) * SS + j)] = e;

        float r = e;
        #pragma unroll
        for (int off = 32; off > 0; off >>= 1) r += __shfl_xor(r, off, 64);
        if ((j & 63) == 0) part[ii][w] = r;
    }
    __syncthreads();

    #pragma unroll
    for (int ii = 0; ii < 4; ++ii) {
        int i = i0 + ii;
        float tot = part[ii][0] + part[ii][1] + part[ii][2] + part[ii][3];
        if (j == heads[b * SS + i])
            ce[b * SS + i] = (i >= 1) ? (__logf(tot) - sv_[ii]) : 0.f;
    }
}

// -------------------------------------------------------------------------
// Kernel 5: deterministic loss reduction: sum(ce)/B into out[0].
// -------------------------------------------------------------------------
__global__ __launch_bounds__(256) void k_loss(const float* __restrict__ ce,
                                              float* __restrict__ out)
{
    __shared__ float red[256];
    int t = threadIdx.x;
    float a = 0.f;
    for (int k = t; k < BB * SS; k += 256) a += ce[k];
    red[t] = a; __syncthreads();
    for (int off = 128; off > 0; off >>= 1) {
        if (t < off) red[t] += red[t + off];
        __syncthreads();
    }
    if (t == 0) out[0] = red[0] * (1.f / BB);
}

extern "C" void kernel_launch(void* const* d_in, const int* in_sizes, int n_in,
                              void* d_out, int out_size, void* d_ws, size_t ws_size,
                              hipStream_t stream)
{
    const int*   words = (const int*)  d_in[0];
    const int*   pos   = (const int*)  d_in[1];
    const float* morph = (const float*)d_in[2];
    const int*   heads = (const int*)  d_in[3];
    const float* wtab  = (const float*)d_in[4];
    const float* ptab  = (const float*)d_in[5];
    const float* Wxf   = (const float*)d_in[6];
    const float* Whf   = (const float*)d_in[7];
    const float* bf    = (const float*)d_in[8];
    const float* Wxb   = (const float*)d_in[9];
    const float* Whb   = (const float*)d_in[10];
    const float* bb    = (const float*)d_in[11];
    const float* Wu    = (const float*)d_in[12];
    const float* bu    = (const float*)d_in[13];
    const float* Ww    = (const float*)d_in[14];
    const float* bw    = (const float*)d_in[15];
    const float* v     = (const float*)d_in[16];
    float* out = (float*)d_out;

    // workspace layout (floats)
    float* xgf  = (float*)d_ws;                  // 8192*24 (prescaled)
    float* xgb  = xgf  + (size_t)BB*SS*G4;       // 8192*24 (prescaled)
    float* ua   = xgb  + (size_t)BB*SS*G4;       // 8192*12 (prescaled 2log2e)
    float* wa   = ua   + (size_t)BB*SS*AA;       // 8192*12 (prescaled 2log2e)
    float* ce   = wa   + (size_t)BB*SS*AA;       // 8192

    k_embed_proj<<<(BB * SS) / EPB, 256, 0, stream>>>(words, pos, morph, wtab, ptab,
                                                      Wxf, bf, Wxb, bb, xgf, xgb);
    k_lstm_uawa<<<BB, 128, 0, stream>>>(xgf, xgb, Whf, Whb, Wu, bu, Ww, bw, ua, wa);
    k_score<<<BB * (SS / 4), 256, 0, stream>>>(ua, wa, v, heads, out, ce);
    k_loss<<<1, 256, 0, stream>>>(ce, out);
}